// Round 4
// baseline (143.704 us; speedup 1.0000x reference)
//
#include <hip/hip_runtime.h>

// Sizes (compile-time constants)
#define NB   131072   // batch
#define ND1  40       // features
#define ND2  10       // timesteps
#define NT0  120
#define NT1  5
#define NO0  3

// One thread per batch element.
// Phase 1: y[d][u] = sum_s x[b,d,s] * fc2_w[u,s]          (2000 FMA)
// Phase 2: z[t][u] = bias1[t,u] + sum_d W11[t,d]*y[d][u]  (24000 FMA)
//          s_t = sum_u fc4_w[u]*relu(z[t][u])
//          out[o] += W12[o,t]*s_t                          (~1560 ops)
__global__ __launch_bounds__(256, 2) void BL_36721970381090_kernel(
    const float* __restrict__ x,
    const float* __restrict__ W11,
    const float* __restrict__ fc2_w,
    const float* __restrict__ bias1,
    const float* __restrict__ W12,
    const float* __restrict__ fc4_w,
    const float* __restrict__ bias2,
    float* __restrict__ out)
{
    const int b = blockIdx.x * blockDim.x + threadIdx.x;
    if (b >= NB) return;

    const float* __restrict__ xb = x + (size_t)b * (ND1 * ND2);

    // ---- Phase 1: y = x[b] @ fc2_w^T  -> [40][5], kept in registers ----
    float y[ND1][NT1];

    // Process d in pairs so each step loads 20 floats = 5 aligned float4
    // (row start is b*1600 B, 16B-aligned; 2 rows = 80 B = 5*16B).
#pragma unroll
    for (int dd = 0; dd < ND1; dd += 2) {
        float4 xv[5];
        const float4* p = reinterpret_cast<const float4*>(xb + dd * ND2);
#pragma unroll
        for (int i = 0; i < 5; ++i) xv[i] = p[i];
        const float* xs = reinterpret_cast<const float*>(xv);
#pragma unroll
        for (int k = 0; k < 2; ++k) {
#pragma unroll
            for (int u = 0; u < NT1; ++u) {
                float acc = 0.f;
#pragma unroll
                for (int s = 0; s < ND2; ++s)
                    acc = fmaf(xs[k * ND2 + s], fc2_w[u * ND2 + s], acc);
                y[dd + k][u] = acc;
            }
        }
    }

    // ---- Phase 2: t-loop, all weight reads are wave-uniform (scalar) ----
    float o0 = 0.f, o1 = 0.f, o2 = 0.f;
    for (int t = 0; t < NT0; ++t) {
        float z[NT1];
#pragma unroll
        for (int u = 0; u < NT1; ++u) z[u] = bias1[t * NT1 + u];

#pragma unroll
        for (int d = 0; d < ND1; ++d) {
            const float w = W11[t * ND1 + d];
#pragma unroll
            for (int u = 0; u < NT1; ++u)
                z[u] = fmaf(w, y[d][u], z[u]);
        }

        float st = 0.f;
#pragma unroll
        for (int u = 0; u < NT1; ++u) {
            const float r = fmaxf(z[u], 0.f);
            st = fmaf(fc4_w[u], r, st);
        }
        o0 = fmaf(W12[0 * NT0 + t], st, o0);
        o1 = fmaf(W12[1 * NT0 + t], st, o1);
        o2 = fmaf(W12[2 * NT0 + t], st, o2);
    }

    out[(size_t)b * NO0 + 0] = o0 + bias2[0];
    out[(size_t)b * NO0 + 1] = o1 + bias2[1];
    out[(size_t)b * NO0 + 2] = o2 + bias2[2];
}

extern "C" void kernel_launch(void* const* d_in, const int* in_sizes, int n_in,
                              void* d_out, int out_size, void* d_ws, size_t ws_size,
                              hipStream_t stream) {
    const float* x      = (const float*)d_in[0];
    const float* W11    = (const float*)d_in[1];
    const float* fc2_w  = (const float*)d_in[2];
    const float* bias1  = (const float*)d_in[3];
    const float* W12    = (const float*)d_in[4];
    const float* fc4_w  = (const float*)d_in[5];
    const float* bias2  = (const float*)d_in[6];
    float* out = (float*)d_out;

    const int threads = 256;
    const int blocks  = NB / threads;  // 131072/256 = 512
    BL_36721970381090_kernel<<<blocks, threads, 0, stream>>>(
        x, W11, fc2_w, bias1, W12, fc4_w, bias2, out);
}

// Round 7
// 137.516 us; speedup vs baseline: 1.0450x; 1.0450x over previous
//
#include <hip/hip_runtime.h>

// Sizes (compile-time constants)
#define NB   131072   // batch
#define ND1  40       // features
#define ND2  10       // timesteps
#define NT0  120
#define NT1  5
#define NO0  3

// Two threads per batch element (lane pair 2i, 2i+1 via h = tid&1).
// Each lane owns half the d-dimension (20 rows) so y_half[20][5] = 100 VGPRs
// stays register-resident inside the <=128-VGPR tier (4 waves/SIMD).
//
// Phase 1: y[dl][u] = sum_s x[b, h*20+dl, s] * fc2_w[u,s]    (1000 FMA)
// Phase 2: z[u]     = sum_dl W11[t, h*20+dl] * y[dl][u]      (100 FMA/t)
//          combine z across the lane pair with __shfl_xor(1),
//          add bias1, ReLU, fold fc4 and W12 into 3 output accumulators.
__global__ __launch_bounds__(256, 4) void BL_36721970381090_kernel(
    const float* __restrict__ x,
    const float* __restrict__ W11,
    const float* __restrict__ fc2_w,
    const float* __restrict__ bias1,
    const float* __restrict__ W12,
    const float* __restrict__ fc4_w,
    const float* __restrict__ bias2,
    float* __restrict__ out)
{
    const int tid = blockIdx.x * blockDim.x + threadIdx.x;   // 0 .. 2*NB-1
    const int b   = tid >> 1;
    const int h   = tid & 1;

    // This lane's half-row block: x + b*400 + h*200 = tid*200 floats (800 B,
    // 16B-aligned, lane-contiguous across the wave).
    const float* __restrict__ xb = x + (size_t)tid * (ND1 * ND2 / 2);

    // ---- Phase 1: y_half = x_half @ fc2_w^T -> [20][5] in registers ----
    float y[20][NT1];
#pragma unroll
    for (int c = 0; c < 10; ++c) {            // 2 d-rows (20 floats) per chunk
        float4 xv[5];
        const float4* p = reinterpret_cast<const float4*>(xb + c * 20);
#pragma unroll
        for (int i = 0; i < 5; ++i) xv[i] = p[i];
        const float* xs = reinterpret_cast<const float*>(xv);
#pragma unroll
        for (int k = 0; k < 2; ++k) {
#pragma unroll
            for (int u = 0; u < NT1; ++u) {
                float acc = 0.f;
#pragma unroll
                for (int s = 0; s < ND2; ++s)
                    acc = fmaf(xs[k * ND2 + s], fc2_w[u * ND2 + s], acc);
                y[c * 2 + k][u] = acc;
            }
        }
    }

    // ---- Phase 2: t-loop; W11 half-row loaded as 5 float4 (one live at a
    // time to keep peak pressure under the 128-VGPR tier) ----
    const float4* __restrict__ W11f4 = reinterpret_cast<const float4*>(W11);
    float o0 = 0.f, o1 = 0.f, o2 = 0.f;
    for (int t = 0; t < NT0; ++t) {
        float z[NT1] = {0.f, 0.f, 0.f, 0.f, 0.f};
#pragma unroll
        for (int q = 0; q < 5; ++q) {
            const float4 w4 = W11f4[t * 10 + h * 5 + q];  // W11[t][h*20+4q ..]
            const float* ws = reinterpret_cast<const float*>(&w4);
#pragma unroll
            for (int j = 0; j < 4; ++j) {
#pragma unroll
                for (int u = 0; u < NT1; ++u)
                    z[u] = fmaf(ws[j], y[q * 4 + j][u], z[u]);
            }
        }

        float st = 0.f;
#pragma unroll
        for (int u = 0; u < NT1; ++u) {
            const float zp = __shfl_xor(z[u], 1, 64);     // partner's half-sum
            const float zf = z[u] + zp + bias1[t * NT1 + u];
            st = fmaf(fc4_w[u], fmaxf(zf, 0.f), st);
        }
        o0 = fmaf(W12[0 * NT0 + t], st, o0);
        o1 = fmaf(W12[1 * NT0 + t], st, o1);
        o2 = fmaf(W12[2 * NT0 + t], st, o2);
    }

    if (h == 0) {
        out[(size_t)b * NO0 + 0] = o0 + bias2[0];
        out[(size_t)b * NO0 + 1] = o1 + bias2[1];
        out[(size_t)b * NO0 + 2] = o2 + bias2[2];
    }
}

extern "C" void kernel_launch(void* const* d_in, const int* in_sizes, int n_in,
                              void* d_out, int out_size, void* d_ws, size_t ws_size,
                              hipStream_t stream) {
    const float* x      = (const float*)d_in[0];
    const float* W11    = (const float*)d_in[1];
    const float* fc2_w  = (const float*)d_in[2];
    const float* bias1  = (const float*)d_in[3];
    const float* W12    = (const float*)d_in[4];
    const float* fc4_w  = (const float*)d_in[5];
    const float* bias2  = (const float*)d_in[6];
    float* out = (float*)d_out;

    const int threads = 256;
    const int blocks  = (2 * NB) / threads;   // 262144/256 = 1024
    BL_36721970381090_kernel<<<blocks, threads, 0, stream>>>(
        x, W11, fc2_w, bias1, W12, fc4_w, bias2, out);
}

// Round 9
// 108.931 us; speedup vs baseline: 1.3192x; 1.2624x over previous
//
#include <hip/hip_runtime.h>

// Problem sizes
#define NB  131072   // batch
#define ND1 40       // features (GEMM K, zero-padded to 64)
#define ND2 10       // timesteps
#define NT0 120      // template rows (GEMM M, zero-padded to 128)
#define NT1 5        // u
#define NO0 3        // outputs

#define NBW 64       // batches per workgroup (GEMM N)
#define PK  72       // Ybf row pitch in bf16 elems (144 B, 16B-aligned rows)

typedef __attribute__((ext_vector_type(8))) short  short8;  // 8 bf16 = MFMA A/B frag
typedef __attribute__((ext_vector_type(4))) float  f32x4;   // MFMA C/D frag

static __device__ __forceinline__ unsigned short f2bf(float f) {
    union { float f; unsigned u; } v; v.f = f;
    unsigned r = v.u + 0x7FFFu + ((v.u >> 16) & 1u);   // round-to-nearest-even
    return (unsigned short)(r >> 16);
}

// Per 64-batch tile:
//  phase 1 (VALU fp32): y[d][u] = sum_s x[b,d,s]*fc2_w[u,s]; store bf16 Y^T
//          [u][b_local][d] in LDS (d contiguous -> one ds_read_b128 = B-frag).
//  phase 2 (MFMA bf16): per u: Z[t,b] = sum_d W11[t,d]*Y_u[d,b] via
//          mfma_f32_16x16x32_bf16, A=W11 frags from global (masked bf16),
//          fused epilogue st[t,b] += fc4[u]*relu(Z+bias1[t,u]).
//  epilogue: out[o,b] = sum_t W12[o,t]*st[t,b]  (in-lane + shfl + LDS reduce).
__global__ __launch_bounds__(256, 3) void BL_36721970381090_kernel(
    const float* __restrict__ x,
    const float* __restrict__ W11,
    const float* __restrict__ fc2_w,
    const float* __restrict__ bias1,
    const float* __restrict__ W12,
    const float* __restrict__ fc4_w,
    const float* __restrict__ bias2,
    float* __restrict__ out)
{
    __shared__ __align__(16) unsigned short Ybf[NT1 * NBW * PK];  // 46080 B
    __shared__ float redL[4 * NO0 * NBW];                         //  3072 B

    const int tid = threadIdx.x;
    const int wg  = blockIdx.x;

    // ---------------- phase 1: per-thread y (10 d-rows, all 5 u) ----------
    {
        const int bl = tid >> 2;                    // batch slot 0..63
        const int q  = tid & 3;                     // d-quarter (rows q*10..+9)
        const float* xb = x + (size_t)(wg * NBW + bl) * (ND1 * ND2) + q * 100;

        float y[10][NT1];
#pragma unroll
        for (int g = 0; g < 5; ++g) {               // 2 d-rows (20 floats)/chunk
            float4 xv[5];
            const float4* p = (const float4*)(xb + g * 20);
#pragma unroll
            for (int i = 0; i < 5; ++i) xv[i] = p[i];
            const float* xs = (const float*)xv;
#pragma unroll
            for (int k = 0; k < 2; ++k)
#pragma unroll
                for (int u = 0; u < NT1; ++u) {
                    float a = 0.f;
#pragma unroll
                    for (int s = 0; s < ND2; ++s)
                        a = fmaf(xs[k * ND2 + s], fc2_w[u * ND2 + s], a);
                    y[g * 2 + k][u] = a;
                }
        }
        // store Y^T bf16: row = batch slot, col = d (k-dim), + zero pad 40..63
#pragma unroll
        for (int u = 0; u < NT1; ++u) {
            unsigned* dst = (unsigned*)&Ybf[u * (NBW * PK) + bl * PK + q * 10];
#pragma unroll
            for (int g = 0; g < 5; ++g)
                dst[g] = (unsigned)f2bf(y[2 * g][u]) |
                         ((unsigned)f2bf(y[2 * g + 1][u]) << 16);
            unsigned* pz = (unsigned*)&Ybf[u * (NBW * PK) + bl * PK + 40 + q * 6];
            pz[0] = 0u; pz[1] = 0u; pz[2] = 0u;     // cols 40+q*6 .. 45+q*6
        }
    }

    // ---------------- A-fragments: W11 -> bf16, masked (t<120, d<40) ------
    const int w  = tid >> 6;    // wave 0..3: t-rows [w*32, w*32+32)
    const int l  = tid & 63;
    const int lr = l & 15;      // A row / B col within 16-tile
    const int lg = l >> 4;      // k-group (8 contiguous k per group)

    short8 afr[2][2];           // [m-tile][k-tile]
#pragma unroll
    for (int mt = 0; mt < 2; ++mt) {
        const int t  = w * 32 + mt * 16 + lr;
        const int tc = t < NT0 ? t : NT0 - 1;
#pragma unroll
        for (int kk = 0; kk < 2; ++kk) {
            const int cb = kk * 32 + lg * 8;        // k-base 0..56
            const int cc = cb <= 32 ? cb : 0;       // clamp (row is 40 wide)
            const float4* pw = (const float4*)(W11 + tc * ND1 + cc);
            const float4 w0 = pw[0], w1 = pw[1];
            const bool v = (t < NT0) && (cb <= 32); // cb<=32 -> cols <=39 valid
            short8 f;
            f[0] = v ? (short)f2bf(w0.x) : (short)0;
            f[1] = v ? (short)f2bf(w0.y) : (short)0;
            f[2] = v ? (short)f2bf(w0.z) : (short)0;
            f[3] = v ? (short)f2bf(w0.w) : (short)0;
            f[4] = v ? (short)f2bf(w1.x) : (short)0;
            f[5] = v ? (short)f2bf(w1.y) : (short)0;
            f[6] = v ? (short)f2bf(w1.z) : (short)0;
            f[7] = v ? (short)f2bf(w1.w) : (short)0;
            afr[mt][kk] = f;
        }
    }

    __syncthreads();

    // ---------------- phase 2: MFMA + fused relu/fc4 ----------------------
    float st[2][4][4];          // [m-tile][n-tile][reg] = st[t, b] fragments
#pragma unroll
    for (int mt = 0; mt < 2; ++mt)
#pragma unroll
        for (int nt = 0; nt < 4; ++nt)
#pragma unroll
            for (int r = 0; r < 4; ++r) st[mt][nt][r] = 0.f;

#pragma unroll
    for (int u = 0; u < NT1; ++u) {
        const float fu = fc4_w[u];                  // wave-uniform scalar
        float bv[2][4];
#pragma unroll
        for (int mt = 0; mt < 2; ++mt)
#pragma unroll
            for (int r = 0; r < 4; ++r) {
                const int t = w * 32 + mt * 16 + lg * 4 + r;
                bv[mt][r] = (t < NT0) ? bias1[t * NT1 + u] : 0.f;
            }
        const unsigned short* Yu = &Ybf[u * (NBW * PK)];
#pragma unroll
        for (int nt = 0; nt < 4; ++nt) {
            const short8 b0 = *(const short8*)&Yu[(nt * 16 + lr) * PK + lg * 8];
            const short8 b1 = *(const short8*)&Yu[(nt * 16 + lr) * PK + 32 + lg * 8];
#pragma unroll
            for (int mt = 0; mt < 2; ++mt) {
                f32x4 z = {0.f, 0.f, 0.f, 0.f};
                z = __builtin_amdgcn_mfma_f32_16x16x32_bf16(afr[mt][0], b0, z, 0, 0, 0);
                z = __builtin_amdgcn_mfma_f32_16x16x32_bf16(afr[mt][1], b1, z, 0, 0, 0);
#pragma unroll
                for (int r = 0; r < 4; ++r)
                    st[mt][nt][r] += fu * fmaxf(z[r] + bv[mt][r], 0.f);
            }
        }
    }

    // ---------------- epilogue: out[o,b] = sum_t W12[o,t]*st[t,b] ---------
    float w12v[NO0][2][4];
#pragma unroll
    for (int o = 0; o < NO0; ++o)
#pragma unroll
        for (int mt = 0; mt < 2; ++mt)
#pragma unroll
            for (int r = 0; r < 4; ++r) {
                const int t = w * 32 + mt * 16 + lg * 4 + r;
                w12v[o][mt][r] = (t < NT0) ? W12[o * NT0 + t] : 0.f;
            }

    float po[4][NO0];
#pragma unroll
    for (int nt = 0; nt < 4; ++nt)
#pragma unroll
        for (int o = 0; o < NO0; ++o) {
            float a = 0.f;
#pragma unroll
            for (int mt = 0; mt < 2; ++mt)
#pragma unroll
                for (int r = 0; r < 4; ++r)
                    a = fmaf(w12v[o][mt][r], st[mt][nt][r], a);
            a += __shfl_xor(a, 16, 64);   // reduce over k-groups (t-rows)
            a += __shfl_xor(a, 32, 64);
            po[nt][o] = a;
        }

    if (l < 16) {
#pragma unroll
        for (int nt = 0; nt < 4; ++nt)
#pragma unroll
            for (int o = 0; o < NO0; ++o)
                redL[(w * NO0 + o) * NBW + nt * 16 + l] = po[nt][o];
    }
    __syncthreads();

    if (tid < NO0 * NBW) {                 // 192 threads
        const int o  = tid >> 6;
        const int bc = tid & 63;
        const float s = redL[(0 * NO0 + o) * NBW + bc]
                      + redL[(1 * NO0 + o) * NBW + bc]
                      + redL[(2 * NO0 + o) * NBW + bc]
                      + redL[(3 * NO0 + o) * NBW + bc]
                      + bias2[o];
        out[(size_t)(wg * NBW + bc) * NO0 + o] = s;
    }
}

extern "C" void kernel_launch(void* const* d_in, const int* in_sizes, int n_in,
                              void* d_out, int out_size, void* d_ws, size_t ws_size,
                              hipStream_t stream) {
    const float* x      = (const float*)d_in[0];
    const float* W11    = (const float*)d_in[1];
    const float* fc2_w  = (const float*)d_in[2];
    const float* bias1  = (const float*)d_in[3];
    const float* W12    = (const float*)d_in[4];
    const float* fc4_w  = (const float*)d_in[5];
    const float* bias2  = (const float*)d_in[6];
    float* out = (float*)d_out;

    const int blocks = NB / NBW;   // 2048
    BL_36721970381090_kernel<<<blocks, 256, 0, stream>>>(
        x, W11, fc2_w, bias1, W12, fc4_w, bias2, out);
}